// Round 1
// baseline (1601.950 us; speedup 1.0000x reference)
//
#include <hip/hip_runtime.h>

#define N_NODES 50000
#define IN_DIM 512
#define HIDDEN 64
#define OUT_DIM 47

union F4 { float4 v; float f[4]; };

// ---------------------------------------------------------------------------
// K1: h0 = relu(x @ embed_w + embed_b)   [50000,512]@[512,64]
// thread = 4 rows x 4 cols; tid in [0, 12500*16)
// ---------------------------------------------------------------------------
__global__ __launch_bounds__(256) void embed_gemm(
    const float* __restrict__ x, const float* __restrict__ w,
    const float* __restrict__ b, float* __restrict__ h0) {
  int tid = blockIdx.x * 256 + threadIdx.x;
  if (tid >= (N_NODES / 4) * 16) return;
  int rb = tid >> 4;   // row block
  int jg = tid & 15;   // col group of 4
  int r0 = rb * 4;

  float acc[4][4];
#pragma unroll
  for (int r = 0; r < 4; r++)
#pragma unroll
    for (int j = 0; j < 4; j++) acc[r][j] = 0.f;

  const float4* xr0 = (const float4*)(x + (size_t)(r0 + 0) * IN_DIM);
  const float4* xr1 = (const float4*)(x + (size_t)(r0 + 1) * IN_DIM);
  const float4* xr2 = (const float4*)(x + (size_t)(r0 + 2) * IN_DIM);
  const float4* xr3 = (const float4*)(x + (size_t)(r0 + 3) * IN_DIM);

  for (int k4 = 0; k4 < IN_DIM / 4; k4++) {
    F4 xv[4];
    xv[0].v = xr0[k4];
    xv[1].v = xr1[k4];
    xv[2].v = xr2[k4];
    xv[3].v = xr3[k4];
#pragma unroll
    for (int i = 0; i < 4; i++) {
      F4 wv;
      wv.v = *(const float4*)(w + (size_t)(k4 * 4 + i) * HIDDEN + jg * 4);
#pragma unroll
      for (int r = 0; r < 4; r++) {
        float xs = xv[r].f[i];
        acc[r][0] += xs * wv.f[0];
        acc[r][1] += xs * wv.f[1];
        acc[r][2] += xs * wv.f[2];
        acc[r][3] += xs * wv.f[3];
      }
    }
  }

  F4 bv;
  bv.v = *(const float4*)(b + jg * 4);
#pragma unroll
  for (int r = 0; r < 4; r++) {
    F4 o;
#pragma unroll
    for (int j = 0; j < 4; j++) {
      float v = acc[r][j] + bv.f[j];
      o.f[j] = v > 0.f ? v : 0.f;
    }
    *(float4*)(h0 + (size_t)(r0 + r) * HIDDEN + jg * 4) = o.v;
  }
}

// ---------------------------------------------------------------------------
// SpMM (scatter-atomic): out[dst[e], coff + c] += w[e] * h[src[e], c]
// ---------------------------------------------------------------------------
template <int F>
__global__ __launch_bounds__(256) void spmm_atomic(
    const int* __restrict__ src, const int* __restrict__ dst,
    const float* __restrict__ w, int E, const float* __restrict__ h,
    int hstride, float* __restrict__ out, int ostride, int coff) {
  long long total = (long long)E * F;
  long long stride = (long long)gridDim.x * blockDim.x;
  for (long long i = (long long)blockIdx.x * blockDim.x + threadIdx.x;
       i < total; i += stride) {
    int e = (int)(i / F);
    int c = (int)(i % F);
    int s = src[e];
    int d = dst[e];
    float wt = w[e];
    atomicAdd(out + (size_t)d * ostride + coff + c,
              wt * h[(size_t)s * hstride + c]);
  }
}

// ---------------------------------------------------------------------------
// ReLU in place over n4 float4s
// ---------------------------------------------------------------------------
__global__ __launch_bounds__(256) void relu_k(float* __restrict__ p, int n4) {
  int stride = gridDim.x * blockDim.x;
  for (int i = blockIdx.x * 256 + threadIdx.x; i < n4; i += stride) {
    F4 v;
    v.v = ((const float4*)p)[i];
#pragma unroll
    for (int j = 0; j < 4; j++) v.f[j] = v.f[j] > 0.f ? v.f[j] : 0.f;
    ((float4*)p)[i] = v.v;
  }
}

// ---------------------------------------------------------------------------
// Pad cls_w [448,47] -> wpad [448,48] (col 47 zeroed)
// ---------------------------------------------------------------------------
__global__ __launch_bounds__(256) void pad_w(const float* __restrict__ cls_w,
                                             float* __restrict__ wpad) {
  int idx = blockIdx.x * 256 + threadIdx.x;
  if (idx >= 448 * 48) return;
  int k = idx / 48;
  int j = idx % 48;
  wpad[idx] = (j < 47) ? cls_w[k * 47 + j] : 0.f;
}

// ---------------------------------------------------------------------------
// Final GEMM: out[row, :] = [h0|hA|hB][row, :] @ wpad + cls_b
// thread = (row, jg of 4 cols); tid in [0, 50000*12)
// ---------------------------------------------------------------------------
__device__ inline void seg_acc(const float* __restrict__ hrow,
                               const float* __restrict__ wpad, int kbase,
                               int nk4, int jg, float acc[4]) {
  const float4* h4 = (const float4*)hrow;
  for (int k4 = 0; k4 < nk4; k4++) {
    F4 hv;
    hv.v = h4[k4];
#pragma unroll
    for (int i = 0; i < 4; i++) {
      F4 wv;
      wv.v = *(const float4*)(wpad + (size_t)(kbase + k4 * 4 + i) * 48 + jg * 4);
      float hs = hv.f[i];
      acc[0] += hs * wv.f[0];
      acc[1] += hs * wv.f[1];
      acc[2] += hs * wv.f[2];
      acc[3] += hs * wv.f[3];
    }
  }
}

__global__ __launch_bounds__(256) void final_gemm(
    const float* __restrict__ h0, const float* __restrict__ hA,
    const float* __restrict__ hB, const float* __restrict__ wpad,
    const float* __restrict__ bias, float* __restrict__ out) {
  int tid = blockIdx.x * 256 + threadIdx.x;
  if (tid >= N_NODES * 12) return;
  int row = tid / 12;
  int jg = tid % 12;

  float acc[4] = {0.f, 0.f, 0.f, 0.f};
  seg_acc(h0 + (size_t)row * 64, wpad, 0, 16, jg, acc);
  seg_acc(hA + (size_t)row * 128, wpad, 64, 32, jg, acc);
  seg_acc(hB + (size_t)row * 256, wpad, 192, 64, jg, acc);

#pragma unroll
  for (int i = 0; i < 4; i++) {
    int j = jg * 4 + i;
    if (j < OUT_DIM) out[(size_t)row * OUT_DIM + j] = acc[i] + bias[j];
  }
}

// ---------------------------------------------------------------------------
extern "C" void kernel_launch(void* const* d_in, const int* in_sizes, int n_in,
                              void* d_out, int out_size, void* d_ws,
                              size_t ws_size, hipStream_t stream) {
  const float* x       = (const float*)d_in[0];
  const int*   src1    = (const int*)d_in[1];
  const int*   dst1    = (const int*)d_in[2];
  const float* w1      = (const float*)d_in[3];
  const int*   src2    = (const int*)d_in[4];
  const int*   dst2    = (const int*)d_in[5];
  const float* w2      = (const float*)d_in[6];
  const float* embed_w = (const float*)d_in[7];
  const float* embed_b = (const float*)d_in[8];
  const float* cls_w   = (const float*)d_in[9];
  const float* cls_b   = (const float*)d_in[10];
  int E1 = in_sizes[1];
  int E2 = in_sizes[4];

  float* ws   = (float*)d_ws;
  float* h0   = ws;                       // 50000*64  = 3,200,000
  float* hA   = h0 + 3200000;             // 50000*128 = 6,400,000
  float* hB   = hA + 6400000;             // 50000*256 = 12,800,000
  float* wpad = hB + 12800000;            // 448*48    = 21,504

  // zero the spmm accumulators (hA + hB contiguous)
  hipMemsetAsync(hA, 0, (size_t)(6400000 + 12800000) * sizeof(float), stream);

  embed_gemm<<<782, 256, 0, stream>>>(x, embed_w, embed_b, h0);
  pad_w<<<(448 * 48 + 255) / 256, 256, 0, stream>>>(cls_w, wpad);

  // k = 1
  spmm_atomic<64><<<2048, 256, 0, stream>>>(src1, dst1, w1, E1, h0, 64, hA, 128, 0);
  spmm_atomic<64><<<2048, 256, 0, stream>>>(src2, dst2, w2, E2, h0, 64, hA, 128, 64);
  relu_k<<<2048, 256, 0, stream>>>(hA, 6400000 / 4);

  // k = 2
  spmm_atomic<128><<<2048, 256, 0, stream>>>(src1, dst1, w1, E1, hA, 128, hB, 256, 0);
  spmm_atomic<128><<<2048, 256, 0, stream>>>(src2, dst2, w2, E2, hA, 128, hB, 256, 128);
  relu_k<<<2048, 256, 0, stream>>>(hB, 12800000 / 4);

  final_gemm<<<2344, 256, 0, stream>>>(h0, hA, hB, wpad, cls_b, (float*)d_out);
}

// Round 2
// 790.994 us; speedup vs baseline: 2.0252x; 2.0252x over previous
//
#include <hip/hip_runtime.h>

#define N_NODES 50000
#define IN_DIM 512
#define HIDDEN 64
#define OUT_DIM 47

union F4 { float4 v; float f[4]; };

// ---------------------------------------------------------------------------
// K1: h0 = relu(x @ embed_w + embed_b)   [50000,512]@[512,64]
// ---------------------------------------------------------------------------
__global__ __launch_bounds__(256) void embed_gemm(
    const float* __restrict__ x, const float* __restrict__ w,
    const float* __restrict__ b, float* __restrict__ h0) {
  int tid = blockIdx.x * 256 + threadIdx.x;
  if (tid >= (N_NODES / 4) * 16) return;
  int rb = tid >> 4;
  int jg = tid & 15;
  int r0 = rb * 4;

  float acc[4][4];
#pragma unroll
  for (int r = 0; r < 4; r++)
#pragma unroll
    for (int j = 0; j < 4; j++) acc[r][j] = 0.f;

  const float4* xr0 = (const float4*)(x + (size_t)(r0 + 0) * IN_DIM);
  const float4* xr1 = (const float4*)(x + (size_t)(r0 + 1) * IN_DIM);
  const float4* xr2 = (const float4*)(x + (size_t)(r0 + 2) * IN_DIM);
  const float4* xr3 = (const float4*)(x + (size_t)(r0 + 3) * IN_DIM);

  for (int k4 = 0; k4 < IN_DIM / 4; k4++) {
    F4 xv[4];
    xv[0].v = xr0[k4];
    xv[1].v = xr1[k4];
    xv[2].v = xr2[k4];
    xv[3].v = xr3[k4];
#pragma unroll
    for (int i = 0; i < 4; i++) {
      F4 wv;
      wv.v = *(const float4*)(w + (size_t)(k4 * 4 + i) * HIDDEN + jg * 4);
#pragma unroll
      for (int r = 0; r < 4; r++) {
        float xs = xv[r].f[i];
        acc[r][0] += xs * wv.f[0];
        acc[r][1] += xs * wv.f[1];
        acc[r][2] += xs * wv.f[2];
        acc[r][3] += xs * wv.f[3];
      }
    }
  }

  F4 bv;
  bv.v = *(const float4*)(b + jg * 4);
#pragma unroll
  for (int r = 0; r < 4; r++) {
    F4 o;
#pragma unroll
    for (int j = 0; j < 4; j++) {
      float v = acc[r][j] + bv.f[j];
      o.f[j] = v > 0.f ? v : 0.f;
    }
    *(float4*)(h0 + (size_t)(r0 + r) * HIDDEN + jg * 4) = o.v;
  }
}

// ---------------------------------------------------------------------------
// CSR build step 1: histogram of dst
// ---------------------------------------------------------------------------
__global__ __launch_bounds__(256) void count_edges(const int* __restrict__ dst,
                                                   int E, int* __restrict__ cnt) {
  int stride = gridDim.x * blockDim.x;
  for (int e = blockIdx.x * 256 + threadIdx.x; e < E; e += stride)
    atomicAdd(&cnt[dst[e]], 1);
}

// ---------------------------------------------------------------------------
// CSR build step 2: in-place exclusive scan of two 50000-int arrays.
// Launch with 2 blocks x 1024 threads; blockIdx selects the array.
// ---------------------------------------------------------------------------
__global__ __launch_bounds__(1024) void exscan2(int* a0, int n0, int* a1, int n1) {
  int* a = blockIdx.x ? a1 : a0;
  int n = blockIdx.x ? n1 : n0;
  int tid = threadIdx.x;
  int lane = tid & 63;
  int wid = tid >> 6;  // 16 waves

  __shared__ int wsum[16];
  __shared__ int carry_s, tot_s;
  if (tid == 0) carry_s = 0;
  __syncthreads();

  for (int base = 0; base < n; base += 1024) {
    int i = base + tid;
    int v0 = (i < n) ? a[i] : 0;
    int v = v0;
#pragma unroll
    for (int off = 1; off < 64; off <<= 1) {
      int t = __shfl_up(v, off, 64);
      if (lane >= off) v += t;
    }
    if (lane == 63) wsum[wid] = v;
    __syncthreads();
    if (wid == 0 && lane < 16) {
      int s = wsum[lane], sc = s;
#pragma unroll
      for (int off = 1; off < 16; off <<= 1) {
        int t = __shfl_up(sc, off, 16);
        if (lane >= off) sc += t;
      }
      wsum[lane] = sc - s;  // exclusive wave offset
      if (lane == 15) tot_s = sc;
    }
    __syncthreads();
    int excl = carry_s + wsum[wid] + (v - v0);
    if (i < n) a[i] = excl;
    __syncthreads();
    if (tid == 0) carry_s += tot_s;
    __syncthreads();
  }
}

// ---------------------------------------------------------------------------
// CSR build step 3: scatter edges into CSR order (cursor becomes end-ptr)
// ---------------------------------------------------------------------------
__global__ __launch_bounds__(256) void scatter_edges(
    const int* __restrict__ src, const int* __restrict__ dst,
    const float* __restrict__ w, int E, int* __restrict__ cursor,
    int2* __restrict__ ew) {
  int stride = gridDim.x * blockDim.x;
  for (int e = blockIdx.x * 256 + threadIdx.x; e < E; e += stride) {
    int d = dst[e];
    int pos = atomicAdd(&cursor[d], 1);
    ew[pos] = make_int2(src[e], __float_as_int(w[e]));
  }
}

// ---------------------------------------------------------------------------
// Gather SpMM + fused ReLU: out[node, coff+c] = relu(sum_e w*h[src,c])
// endptr[node] = end of node's edge range (start = endptr[node-1], 0 for node 0)
// F = input feature width; F/4 lanes per node, float4 per lane.
// ---------------------------------------------------------------------------
template <int F>
__global__ __launch_bounds__(256) void gather_spmm(
    const int* __restrict__ endptr, const int2* __restrict__ ew,
    const float* __restrict__ h, float* __restrict__ out, int ostride,
    int coff) {
  constexpr int CG = F / 4;
  int tid = blockIdx.x * 256 + threadIdx.x;
  int node = tid / CG;
  int cg = tid % CG;
  if (node >= N_NODES) return;
  int s = (node == 0) ? 0 : endptr[node - 1];
  int e = endptr[node];

  float4 acc = {0.f, 0.f, 0.f, 0.f};
#pragma unroll 2
  for (int j = s; j < e; j++) {
    int2 p = ew[j];
    float wt = __int_as_float(p.y);
    F4 hv;
    hv.v = *(const float4*)(h + (size_t)p.x * F + cg * 4);
    acc.x += wt * hv.f[0];
    acc.y += wt * hv.f[1];
    acc.z += wt * hv.f[2];
    acc.w += wt * hv.f[3];
  }
  F4 o;
  o.f[0] = acc.x > 0.f ? acc.x : 0.f;
  o.f[1] = acc.y > 0.f ? acc.y : 0.f;
  o.f[2] = acc.z > 0.f ? acc.z : 0.f;
  o.f[3] = acc.w > 0.f ? acc.w : 0.f;
  *(float4*)(out + (size_t)node * ostride + coff + cg * 4) = o.v;
}

// ---------------------------------------------------------------------------
// Fallback path kernels (atomic scatter SpMM + relu) — used if ws too small
// ---------------------------------------------------------------------------
template <int F>
__global__ __launch_bounds__(256) void spmm_atomic(
    const int* __restrict__ src, const int* __restrict__ dst,
    const float* __restrict__ w, int E, const float* __restrict__ h,
    int hstride, float* __restrict__ out, int ostride, int coff) {
  long long total = (long long)E * F;
  long long stride = (long long)gridDim.x * blockDim.x;
  for (long long i = (long long)blockIdx.x * blockDim.x + threadIdx.x;
       i < total; i += stride) {
    int e = (int)(i / F);
    int c = (int)(i % F);
    atomicAdd(out + (size_t)dst[e] * ostride + coff + c,
              w[e] * h[(size_t)src[e] * hstride + c]);
  }
}

__global__ __launch_bounds__(256) void relu_k(float* __restrict__ p, int n4) {
  int stride = gridDim.x * blockDim.x;
  for (int i = blockIdx.x * 256 + threadIdx.x; i < n4; i += stride) {
    F4 v;
    v.v = ((const float4*)p)[i];
#pragma unroll
    for (int j = 0; j < 4; j++) v.f[j] = v.f[j] > 0.f ? v.f[j] : 0.f;
    ((float4*)p)[i] = v.v;
  }
}

// ---------------------------------------------------------------------------
// Pad cls_w [448,47] -> wpad [448,48]
// ---------------------------------------------------------------------------
__global__ __launch_bounds__(256) void pad_w(const float* __restrict__ cls_w,
                                             float* __restrict__ wpad) {
  int idx = blockIdx.x * 256 + threadIdx.x;
  if (idx >= 448 * 48) return;
  int k = idx / 48;
  int j = idx % 48;
  wpad[idx] = (j < 47) ? cls_w[k * 47 + j] : 0.f;
}

// ---------------------------------------------------------------------------
// Final GEMM: out[row, :] = [h0|hA|hB][row, :] @ wpad + cls_b
// ---------------------------------------------------------------------------
__device__ inline void seg_acc(const float* __restrict__ hrow,
                               const float* __restrict__ wpad, int kbase,
                               int nk4, int jg, float acc[4]) {
  const float4* h4 = (const float4*)hrow;
  for (int k4 = 0; k4 < nk4; k4++) {
    F4 hv;
    hv.v = h4[k4];
#pragma unroll
    for (int i = 0; i < 4; i++) {
      F4 wv;
      wv.v = *(const float4*)(wpad + (size_t)(kbase + k4 * 4 + i) * 48 + jg * 4);
      float hs = hv.f[i];
      acc[0] += hs * wv.f[0];
      acc[1] += hs * wv.f[1];
      acc[2] += hs * wv.f[2];
      acc[3] += hs * wv.f[3];
    }
  }
}

__global__ __launch_bounds__(256) void final_gemm(
    const float* __restrict__ h0, const float* __restrict__ hA,
    const float* __restrict__ hB, const float* __restrict__ wpad,
    const float* __restrict__ bias, float* __restrict__ out) {
  int tid = blockIdx.x * 256 + threadIdx.x;
  if (tid >= N_NODES * 12) return;
  int row = tid / 12;
  int jg = tid % 12;

  float acc[4] = {0.f, 0.f, 0.f, 0.f};
  seg_acc(h0 + (size_t)row * 64, wpad, 0, 16, jg, acc);
  seg_acc(hA + (size_t)row * 128, wpad, 64, 32, jg, acc);
  seg_acc(hB + (size_t)row * 256, wpad, 192, 64, jg, acc);

#pragma unroll
  for (int i = 0; i < 4; i++) {
    int j = jg * 4 + i;
    if (j < OUT_DIM) out[(size_t)row * OUT_DIM + j] = acc[i] + bias[j];
  }
}

// ---------------------------------------------------------------------------
extern "C" void kernel_launch(void* const* d_in, const int* in_sizes, int n_in,
                              void* d_out, int out_size, void* d_ws,
                              size_t ws_size, hipStream_t stream) {
  const float* x       = (const float*)d_in[0];
  const int*   src1    = (const int*)d_in[1];
  const int*   dst1    = (const int*)d_in[2];
  const float* w1      = (const float*)d_in[3];
  const int*   src2    = (const int*)d_in[4];
  const int*   dst2    = (const int*)d_in[5];
  const float* w2      = (const float*)d_in[6];
  const float* embed_w = (const float*)d_in[7];
  const float* embed_b = (const float*)d_in[8];
  const float* cls_w   = (const float*)d_in[9];
  const float* cls_b   = (const float*)d_in[10];
  int E1 = in_sizes[1];
  int E2 = in_sizes[4];

  float* ws = (float*)d_ws;
  size_t off = 0;
  float* h0 = ws + off;   off += 3200000;   // 50000*64
  float* hA = ws + off;   off += 6400000;   // 50000*128
  float* hB = ws + off;   off += 12800000;  // 50000*256
  float* wpad = ws + off; off += 21504;     // 448*48
  int* cur1 = (int*)(ws + off); off += 50000;
  int* cur2 = (int*)(ws + off); off += 50000;
  int2* ew1 = (int2*)(ws + off); off += (size_t)2 * E1;
  int2* ew2 = (int2*)(ws + off); off += (size_t)2 * E2;
  size_t need_bytes = off * sizeof(float);

  embed_gemm<<<782, 256, 0, stream>>>(x, embed_w, embed_b, h0);
  pad_w<<<(448 * 48 + 255) / 256, 256, 0, stream>>>(cls_w, wpad);

  if (ws_size >= need_bytes) {
    // ---- CSR gather path ----
    hipMemsetAsync(cur1, 0, 2 * 50000 * sizeof(int), stream);
    count_edges<<<2048, 256, 0, stream>>>(dst1, E1, cur1);
    count_edges<<<2048, 256, 0, stream>>>(dst2, E2, cur2);
    exscan2<<<2, 1024, 0, stream>>>(cur1, N_NODES, cur2, N_NODES);
    scatter_edges<<<2048, 256, 0, stream>>>(src1, dst1, w1, E1, cur1, ew1);
    scatter_edges<<<2048, 256, 0, stream>>>(src2, dst2, w2, E2, cur2, ew2);

    // k = 1: hA = relu([A1@h0 | A2@h0])
    gather_spmm<64><<<3125, 256, 0, stream>>>(cur1, ew1, h0, hA, 128, 0);
    gather_spmm<64><<<3125, 256, 0, stream>>>(cur2, ew2, h0, hA, 128, 64);
    // k = 2: hB = relu([A1@hA | A2@hA])
    gather_spmm<128><<<6250, 256, 0, stream>>>(cur1, ew1, hA, hB, 256, 0);
    gather_spmm<128><<<6250, 256, 0, stream>>>(cur2, ew2, hA, hB, 256, 128);
  } else {
    // ---- fallback: atomic scatter path ----
    hipMemsetAsync(hA, 0, (size_t)(6400000 + 12800000) * sizeof(float), stream);
    spmm_atomic<64><<<2048, 256, 0, stream>>>(src1, dst1, w1, E1, h0, 64, hA, 128, 0);
    spmm_atomic<64><<<2048, 256, 0, stream>>>(src2, dst2, w2, E2, h0, 64, hA, 128, 64);
    relu_k<<<2048, 256, 0, stream>>>(hA, 6400000 / 4);
    spmm_atomic<128><<<2048, 256, 0, stream>>>(src1, dst1, w1, E1, hA, 128, hB, 256, 0);
    spmm_atomic<128><<<2048, 256, 0, stream>>>(src2, dst2, w2, E2, hA, 128, hB, 256, 128);
    relu_k<<<2048, 256, 0, stream>>>(hB, 12800000 / 4);
  }

  final_gemm<<<2344, 256, 0, stream>>>(h0, hA, hB, wpad, cls_b, (float*)d_out);
}